// Round 8
// baseline (247.007 us; speedup 1.0000x reference)
//
#include <hip/hip_runtime.h>
#include <hip/hip_bf16.h>

#define GAT_ALPHA 0.2f
#define LOG2E 1.4426950408889634f

typedef float f32x4 __attribute__((ext_vector_type(4)));
typedef int   i32x4 __attribute__((ext_vector_type(4)));
typedef short bf16x8 __attribute__((ext_vector_type(8)));

static constexpr int Nn  = 2048;
static constexpr int FIN = 256;
static constexpr int FO  = 128;

static __device__ __forceinline__ unsigned short f2bf(float x) {
    __hip_bfloat16 h = __float2bfloat16(x);
    return __builtin_bit_cast(unsigned short, h);
}
static __device__ __forceinline__ float bf2f(unsigned short u) {
    unsigned int v = ((unsigned int)u) << 16;
    return __builtin_bit_cast(float, v);
}

// ---------------------------------------------------------------------------
// Kernel 0 (prep): wa = W@a (both halves). Inits md_key[8] = 0 (key of -inf).
// ---------------------------------------------------------------------------
__global__ __launch_bounds__(256) void gat_prep(
        const float* __restrict__ W, const float* __restrict__ a,
        float* __restrict__ wa, unsigned int* __restrict__ md_key)
{
    __shared__ float pr[32][8];
    __shared__ float pd[32][8];
    const int t = threadIdx.x;
    const int kl = t >> 3, seg = t & 7;
    const int k = blockIdx.x * 32 + kl;
    float ps = 0.f, pv = 0.f;
    const float* wr = W + (size_t)k * FO + seg * 16;
    #pragma unroll
    for (int f = 0; f < 16; f += 4) {
        f32x4 wv = *(const f32x4*)(wr + f);
        f32x4 as = *(const f32x4*)(a + seg * 16 + f);
        f32x4 ad = *(const f32x4*)(a + FO + seg * 16 + f);
        ps += wv[0]*as[0] + wv[1]*as[1] + wv[2]*as[2] + wv[3]*as[3];
        pv += wv[0]*ad[0] + wv[1]*ad[1] + wv[2]*ad[2] + wv[3]*ad[3];
    }
    pr[kl][seg] = ps; pd[kl][seg] = pv;
    __syncthreads();
    if (t < 32) {
        float s = 0.f, d = 0.f;
        #pragma unroll
        for (int j = 0; j < 8; ++j) { s += pr[t][j]; d += pd[t][j]; }
        wa[blockIdx.x * 32 + t]       = s;
        wa[256 + blockIdx.x * 32 + t] = d;
    }
    if (blockIdx.x == 0 && t < 8) md_key[t] = 0u;   // key(-inf)
}

// ---------------------------------------------------------------------------
// Kernel pack: adj (int32 {0,1}, 134 MB) -> bitmask (4.2 MB). Pure dense
// stream at the per-CU line ceiling; reading adj once is the HW floor.
// Word w of mask = bits of ints [w*32, w*32+32), bit k = (adj[w*32+k] > 0).
// ---------------------------------------------------------------------------
__global__ __launch_bounds__(256) void gat_pack(
        const int* __restrict__ adj, unsigned int* __restrict__ mask)
{
    const int t = threadIdx.x, lane = t & 63, w = t >> 6;
    const size_t ibase = ((size_t)blockIdx.x * 4 + w) * 2048;
    const int* src = adj + ibase + lane;
    unsigned int myword = 0;
    #pragma unroll
    for (int c = 0; c < 32; ++c) {
        int v = src[(size_t)c * 64];
        unsigned long long m = __ballot(v > 0);
        if (lane == 2 * c)     myword = (unsigned int)m;
        if (lane == 2 * c + 1) myword = (unsigned int)(m >> 32);
    }
    mask[ibase / 32 + lane] = myword;
}

// ---------------------------------------------------------------------------
// Kernel 1: Wp = bf16(h@W) in PACKED MFMA-B-fragment layout:
//   elem index ((b*64 + v)*8 + nt)*512 + lane*8 + e, where for feature f and
//   node n: v=n>>5, nt=f>>4, lane=((n>>3)&3)*16 + (f&15), e=n&7.
// s_src/s_dst fp32-exact via wa; per-batch max(s_dst) via uint atomicMax.
// ---------------------------------------------------------------------------
__global__ __launch_bounds__(256) void gat_wh(
        const float* __restrict__ h, const float* __restrict__ W,
        const float* __restrict__ wa, unsigned short* __restrict__ Wp,
        float* __restrict__ s_src, float* __restrict__ s_dst,
        unsigned int* __restrict__ md_key)
{
    __shared__ unsigned short WT[FO][264];  // [f][k] bf16, padded
    __shared__ float wal[512];
    __shared__ float sred[64][4][2];
    __shared__ float red64[64];
    const int t  = threadIdx.x;
    const int b  = blockIdx.x & 7;
    const int n0 = (blockIdx.x >> 3) << 6;

    if (t < 128) *(f32x4*)&wal[t * 4] = *(const f32x4*)&wa[t * 4];
    #pragma unroll
    for (int c = 0; c < 32; ++c) {
        int flat = c * 1024 + t * 4;
        int k = flat >> 7, f = flat & 127;
        f32x4 wv = *(const f32x4*)&W[flat];
        WT[f + 0][k] = f2bf(wv[0]);
        WT[f + 1][k] = f2bf(wv[1]);
        WT[f + 2][k] = f2bf(wv[2]);
        WT[f + 3][k] = f2bf(wv[3]);
    }
    __syncthreads();

    {
        const int row = t >> 2, seg = t & 3;
        const float* hp  = h + ((size_t)(b * Nn + n0 + row)) * FIN + seg * 64;
        const float* was = &wal[seg * 64];
        const float* wad = &wal[256 + seg * 64];
        float ps = 0.f, pv = 0.f;
        #pragma unroll
        for (int j = 0; j < 64; j += 4) {
            f32x4 hv = *(const f32x4*)(hp + j);
            f32x4 sv = *(const f32x4*)(was + j);
            f32x4 dv = *(const f32x4*)(wad + j);
            ps += hv[0]*sv[0] + hv[1]*sv[1] + hv[2]*sv[2] + hv[3]*sv[3];
            pv += hv[0]*dv[0] + hv[1]*dv[1] + hv[2]*dv[2] + hv[3]*dv[3];
        }
        sred[row][seg][0] = ps;
        sred[row][seg][1] = pv;
    }
    __syncthreads();
    if (t < 64) {
        float s = sred[t][0][0] + sred[t][1][0] + sred[t][2][0] + sred[t][3][0];
        float d = sred[t][0][1] + sred[t][1][1] + sred[t][2][1] + sred[t][3][1];
        s_src[b * Nn + n0 + t] = s;
        s_dst[b * Nn + n0 + t] = d;
        red64[t] = d;
    }
    __syncthreads();
    if (t < 16) red64[t] = fmaxf(fmaxf(red64[t], red64[t + 16]),
                                 fmaxf(red64[t + 32], red64[t + 48]));
    __syncthreads();
    if (t == 0) {
        float m = red64[0];
        #pragma unroll
        for (int j = 1; j < 16; ++j) m = fmaxf(m, red64[j]);
        unsigned int bits = __builtin_bit_cast(unsigned int, m);
        unsigned int key  = (bits & 0x80000000u) ? ~bits : (bits | 0x80000000u);
        atomicMax(md_key + b, key);
    }

    const int w = t >> 6, lane = t & 63, n16 = lane & 15, quad = lane >> 4;
    const float* ha = h + ((size_t)(b * Nn + n0 + w * 16 + n16)) * FIN + quad * 8;
    f32x4 acc[8] = {};
    #pragma unroll
    for (int ks = 0; ks < 8; ++ks) {
        f32x4 h0 = *(const f32x4*)(ha + ks * 32);
        f32x4 h1 = *(const f32x4*)(ha + ks * 32 + 4);
        bf16x8 af;
        af[0] = (short)f2bf(h0[0]); af[1] = (short)f2bf(h0[1]);
        af[2] = (short)f2bf(h0[2]); af[3] = (short)f2bf(h0[3]);
        af[4] = (short)f2bf(h1[0]); af[5] = (short)f2bf(h1[1]);
        af[6] = (short)f2bf(h1[2]); af[7] = (short)f2bf(h1[3]);
        #pragma unroll
        for (int nt = 0; nt < 8; ++nt) {
            bf16x8 bfr = *(const bf16x8*)&WT[nt * 16 + n16][ks * 32 + quad * 8];
            acc[nt] = __builtin_amdgcn_mfma_f32_16x16x32_bf16(af, bfr, acc[nt], 0, 0, 0);
        }
    }
    // packed write: element (f = nt*16+n16, n = n0 + w*16 + quad*4 + rr)
    {
        const int v      = (n0 >> 5) + (w >> 1);
        const int quad_p = ((w & 1) << 1) + (quad >> 1);
        const int eoff   = (quad & 1) << 2;
        #pragma unroll
        for (int nt = 0; nt < 8; ++nt) {
            ushort4 pk;
            pk.x = f2bf(acc[nt][0]); pk.y = f2bf(acc[nt][1]);
            pk.z = f2bf(acc[nt][2]); pk.w = f2bf(acc[nt][3]);
            size_t idx = ((((size_t)(b << 6) + v) * 8 + nt) * 64 + quad_p * 16 + n16) * 8 + eoff;
            *(ushort4*)&Wp[idx] = pk;
        }
    }
}

// ---------------------------------------------------------------------------
// Kernel 2 (v11): counted-vmcnt pipeline, NO full VMEM drain in the loop.
// Grid 256 = 32 i-tiles(64 rows) x 8 batches (batch==XCD), 512 thr =
// 2 row-groups x 4 j-windows, 16 x 128-j tiles. Prologue stages mask
// (16.6 KB) + s_dst (8 KB) to LDS once. Loop VMEM = Wp stage only, held
// TWO tiles deep in registers: ds_write of tile s+1 happens while tile
// s+2's 4 loads are outstanding -> compiler emits s_waitcnt vmcnt(4),
// never vmcnt(0). Barrier = asm lgkmcnt(0) + bare s_barrier (loads stay
// in flight across it). Epilogue identical to v10.
// ---------------------------------------------------------------------------
__global__ __launch_bounds__(512, 1) void gat_attn(
        const unsigned int* __restrict__ mask, const unsigned short* __restrict__ Wp,
        const float* __restrict__ s_src, const float* __restrict__ s_dst,
        const unsigned int* __restrict__ md_key, float* __restrict__ out)
{
    constexpr int AS = 132;                      // accbuf row stride (f32)
    constexpr int MS = 65;                       // mask row stride (words)
    __shared__ __align__(16) float smem_f[2 * 64 * AS];     // 67584 B: stage dbuf / acc slots
    __shared__ __align__(16) unsigned int mlds[64 * MS];    // 16640 B
    __shared__ __align__(16) float dlds[Nn];                // 8192 B
    __shared__ float l_red[64];
    unsigned short* ldsw = (unsigned short*)smem_f;         // 2 x 16384 shorts

    const int t = threadIdx.x, w = t >> 6, lane = t & 63;
    const int n16 = lane & 15, quad = lane >> 4;
    const int rg = w & 1, jwin = w >> 1;         // 2 row-groups x 4 j-windows
    const int b  = blockIdx.x & 7;
    const int i0 = (blockIdx.x >> 3) << 6;

    if (t < 64) l_red[t] = 0.f;

    const unsigned short* wsrc = Wp + ((size_t)b << 18);

    // ---- prologue: stage tile 0 + hold tile 1; mask + d to LDS ----
    f32x4 g0[4], gA[4], gB[4];
    #pragma unroll
    for (int p = 0; p < 4; ++p) g0[p] = *(const f32x4*)(wsrc + p * 4096 + t * 8);
    #pragma unroll
    for (int p = 0; p < 4; ++p) gA[p] = *(const f32x4*)(wsrc + 16384 + p * 4096 + t * 8);
    i32x4 m0, m1;
    {
        const unsigned int* msrc = mask + ((size_t)(b * Nn + i0)) * 64 + t * 8;
        m0 = *(const i32x4*)(msrc);
        m1 = *(const i32x4*)(msrc + 4);
    }
    f32x4 dv = *(const f32x4*)(s_dst + b * Nn + t * 4);

    const unsigned int key = md_key[b];
    const unsigned int mb_ = (key & 0x80000000u) ? (key ^ 0x80000000u) : ~key;
    const float mdb = __builtin_bit_cast(float, mb_);
    const int r0 = i0 + rg * 32 + n16;           // lane's first i-row
    const float ssr0 = s_src[b * Nn + r0];
    const float ssr1 = s_src[b * Nn + r0 + 16];
    const float tm0 = ssr0 + mdb, tm1 = ssr1 + mdb;
    const float mi0 = fmaxf(tm0, GAT_ALPHA * tm0) * LOG2E;
    const float mi1 = fmaxf(tm1, GAT_ALPHA * tm1) * LOG2E;
    const float sL0 = ssr0 * LOG2E, sL1 = ssr1 * LOG2E;
    const int jw = (jwin << 5) + (quad << 3);    // lane's j offset in 128-j tile
    const int mrow0 = (rg * 32 + n16) * MS;
    const int mrow1 = mrow0 + 16 * MS;

    // LDS writes (tile-0 stage, mask, d)
    #pragma unroll
    for (int p = 0; p < 4; ++p) *(f32x4*)&ldsw[p * 4096 + t * 8] = g0[p];
    {
        const int r = t >> 3, c8 = (t & 7) * 8;
        *(i32x4*)&mlds[r * MS + c8]     = m0;
        *(i32x4*)&mlds[r * MS + c8 + 4] = m1;
    }
    *(f32x4*)&dlds[t * 4] = dv;

    f32x4 acc[2][8] = {};
    float ls0 = 0.f, ls1 = 0.f;
    __syncthreads();

    // ---- main loop: 16 x 128-j tiles, 2 per macro pair ----
#define GAT_TILE(S, CUR, GP, GN)                                                \
    {                                                                           \
        const int s_ = (S);                                                     \
        const int j0 = s_ << 7;                                                 \
        /* issue Wp loads for tile s+2 (stay in flight across the barrier) */   \
        if (s_ < 14) {                                                          \
            const unsigned short* src = wsrc + (size_t)(s_ + 2) * 16384;        \
            _Pragma("unroll")                                                   \
            for (int p = 0; p < 4; ++p)                                         \
                GN[p] = *(const f32x4*)(src + p * 4096 + t * 8);                \
        }                                                                       \
        const unsigned int mw0 = mlds[mrow0 + (s_ << 2) + jwin];                \
        const unsigned int mw1 = mlds[mrow1 + (s_ << 2) + jwin];                \
        const unsigned int mb0 = (mw0 >> (quad << 3)) & 0xffu;                  \
        const unsigned int mb1 = (mw1 >> (quad << 3)) & 0xffu;                  \
        f32x4 d0 = *(const f32x4*)&dlds[j0 + jw];                               \
        f32x4 d1 = *(const f32x4*)&dlds[j0 + jw + 4];                           \
        bf16x8 af0, af1;                                                        \
        _Pragma("unroll")                                                       \
        for (int j = 0; j < 4; ++j) {                                           \
            {   float u  = __builtin_fmaf(d0[j], LOG2E, sL0);                   \
                float lr = fmaxf(u, GAT_ALPHA * u);                             \
                float e  = __builtin_amdgcn_exp2f(lr - mi0);                    \
                e = ((mb0 >> j) & 1u) ? e : 0.f;                                \
                unsigned short us = f2bf(e);                                    \
                ls0 += bf2f(us); af0[j] = (short)us; }                          \
            {   float u  = __builtin_fmaf(d1[j], LOG2E, sL0);                   \
                float lr = fmaxf(u, GAT_ALPHA * u);                             \
                float e  = __builtin_amdgcn_exp2f(lr - mi0);                    \
                e = ((mb0 >> (4 + j)) & 1u) ? e : 0.f;                          \
                unsigned short us = f2bf(e);                                    \
                ls0 += bf2f(us); af0[4 + j] = (short)us; }                      \
            {   float u  = __builtin_fmaf(d0[j], LOG2E, sL1);                   \
                float lr = fmaxf(u, GAT_ALPHA * u);                             \
                float e  = __builtin_amdgcn_exp2f(lr - mi1);                    \
                e = ((mb1 >> j) & 1u) ? e : 0.f;                                \
                unsigned short us = f2bf(e);                                    \
                ls1 += bf2f(us); af1[j] = (short)us; }                          \
            {   float u  = __builtin_fmaf(d1[j], LOG2E, sL1);                   \
                float lr = fmaxf(u, GAT_ALPHA * u);                             \
                float e  = __builtin_amdgcn_exp2f(lr - mi1);                    \
                e = ((mb1 >> (4 + j)) & 1u) ? e : 0.f;                          \
                unsigned short us = f2bf(e);                                    \
                ls1 += bf2f(us); af1[4 + j] = (short)us; }                      \
        }                                                                       \
        const unsigned short* bbase = &ldsw[(CUR) * 16384 + (jwin << 12) + (lane << 3)]; \
        _Pragma("unroll")                                                       \
        for (int nt = 0; nt < 8; ++nt) {                                        \
            bf16x8 bfr = *(const bf16x8*)(bbase + (nt << 9));                   \
            acc[0][nt] = __builtin_amdgcn_mfma_f32_16x16x32_bf16(af0, bfr, acc[0][nt], 0, 0, 0); \
            acc[1][nt] = __builtin_amdgcn_mfma_f32_16x16x32_bf16(af1, bfr, acc[1][nt], 0, 0, 0); \
        }                                                                       \
        /* write tile s+1 (loaded last iter) -> compiler waits vmcnt(4) */      \
        if (s_ < 15) {                                                          \
            _Pragma("unroll")                                                   \
            for (int p = 0; p < 4; ++p)                                         \
                *(f32x4*)&ldsw[((CUR) ^ 1) * 16384 + p * 4096 + t * 8] = GP[p]; \
        }                                                                       \
        asm volatile("s_waitcnt lgkmcnt(0)" ::: "memory");                      \
        __builtin_amdgcn_s_barrier();                                           \
    }

    for (int s = 0; s < 16; s += 2) {
        GAT_TILE(s,     0, gA, gB)
        GAT_TILE(s + 1, 1, gB, gA)
    }
#undef GAT_TILE

    // denominator: reduce per-lane partials across quads, atomics per wave
    ls0 += __shfl_xor(ls0, 16); ls0 += __shfl_xor(ls0, 32);
    ls1 += __shfl_xor(ls1, 16); ls1 += __shfl_xor(ls1, 32);
    if (quad == 0) {
        atomicAdd(&l_red[rg * 32 + n16], ls0);
        atomicAdd(&l_red[rg * 32 + 16 + n16], ls1);
    }

    // cross-wave acc reduction: jwin 0/1 write slots A/B; jwin 2/3 add
    float* slot = smem_f + (size_t)(jwin & 1) * (64 * AS);
    const int rbase = rg * 32;
    if (jwin < 2) {
        #pragma unroll
        for (int ig = 0; ig < 2; ++ig)
            #pragma unroll
            for (int nt = 0; nt < 8; ++nt)
                #pragma unroll
                for (int rr = 0; rr < 4; ++rr)
                    slot[(size_t)(rbase + ig * 16 + quad * 4 + rr) * AS + nt * 16 + n16] = acc[ig][nt][rr];
    }
    __syncthreads();
    if (jwin >= 2) {
        #pragma unroll
        for (int ig = 0; ig < 2; ++ig)
            #pragma unroll
            for (int nt = 0; nt < 8; ++nt)
                #pragma unroll
                for (int rr = 0; rr < 4; ++rr)
                    slot[(size_t)(rbase + ig * 16 + quad * 4 + rr) * AS + nt * 16 + n16] += acc[ig][nt][rr];
    }
    __syncthreads();

    // normalize + ELU + coalesced store (64 rows x 128 f)
    float* ob = out + ((size_t)(b * Nn + i0)) * FO;
    #pragma unroll
    for (int c = 0; c < 4; ++c) {
        int flat = c * 2048 + t * 4;
        int m = flat >> 7, f = flat & 127;
        f32x4 v0 = *(const f32x4*)&smem_f[(size_t)m * AS + f];
        f32x4 v1 = *(const f32x4*)&smem_f[(size_t)(64 + m) * AS + f];
        float l = l_red[m];
        f32x4 o;
        #pragma unroll
        for (int j = 0; j < 4; ++j) {
            float x = (v0[j] + v1[j]) / l;
            o[j] = x > 0.f ? x : expm1f(x);
        }
        *(f32x4*)&ob[(size_t)m * FO + f] = o;
    }
}

extern "C" void kernel_launch(void* const* d_in, const int* in_sizes, int n_in,
                              void* d_out, int out_size, void* d_ws, size_t ws_size,
                              hipStream_t stream)
{
    const float* h   = (const float*)d_in[0];
    const int*   adj = (const int*)d_in[1];
    const float* W   = (const float*)d_in[2];
    const float* a   = (const float*)d_in[3];
    float* out = (float*)d_out;

    char* ws = (char*)d_ws;
    unsigned short* Wp  = (unsigned short*)ws;                    // 4 MiB packed
    float* s_src        = (float*)(ws + 4194304);                 // 8 KiB
    float* s_dst        = (float*)(ws + 4259840);                 // 8 KiB
    float* wa           = (float*)(ws + 4325376);                 // 2 KiB
    unsigned int* md_key= (unsigned int*)(ws + 4327424);          // 32 B
    unsigned int* mask  = (unsigned int*)(ws + 8388608);          // 4.2 MiB bitmask

    hipLaunchKernelGGL(gat_prep, dim3(8),    dim3(256), 0, stream, W, a, wa, md_key);
    hipLaunchKernelGGL(gat_wh,   dim3(256),  dim3(256), 0, stream, h, W, wa, Wp, s_src, s_dst, md_key);
    hipLaunchKernelGGL(gat_pack, dim3(4096), dim3(256), 0, stream, adj, mask);
    hipLaunchKernelGGL(gat_attn, dim3(256),  dim3(512), 0, stream, mask, Wp, s_src, s_dst, md_key, out);
}

// Round 9
// 236.256 us; speedup vs baseline: 1.0455x; 1.0455x over previous
//
#include <hip/hip_runtime.h>
#include <hip/hip_bf16.h>

#define GAT_ALPHA 0.2f
#define LOG2E 1.4426950408889634f

typedef float f32x4 __attribute__((ext_vector_type(4)));
typedef int   i32x4 __attribute__((ext_vector_type(4)));
typedef short bf16x8 __attribute__((ext_vector_type(8)));

static constexpr int Nn  = 2048;
static constexpr int FIN = 256;
static constexpr int FO  = 128;

static __device__ __forceinline__ unsigned short f2bf(float x) {
    __hip_bfloat16 h = __float2bfloat16(x);
    return __builtin_bit_cast(unsigned short, h);
}
static __device__ __forceinline__ float bf2f(unsigned short u) {
    unsigned int v = ((unsigned int)u) << 16;
    return __builtin_bit_cast(float, v);
}

// ---------------------------------------------------------------------------
// Kernel 0 (prep): wa = W@a (both halves). Inits md_key[8] = 0 (key of -inf).
// ---------------------------------------------------------------------------
__global__ __launch_bounds__(256) void gat_prep(
        const float* __restrict__ W, const float* __restrict__ a,
        float* __restrict__ wa, unsigned int* __restrict__ md_key)
{
    __shared__ float pr[32][8];
    __shared__ float pd[32][8];
    const int t = threadIdx.x;
    const int kl = t >> 3, seg = t & 7;
    const int k = blockIdx.x * 32 + kl;
    float ps = 0.f, pv = 0.f;
    const float* wr = W + (size_t)k * FO + seg * 16;
    #pragma unroll
    for (int f = 0; f < 16; f += 4) {
        f32x4 wv = *(const f32x4*)(wr + f);
        f32x4 as = *(const f32x4*)(a + seg * 16 + f);
        f32x4 ad = *(const f32x4*)(a + FO + seg * 16 + f);
        ps += wv[0]*as[0] + wv[1]*as[1] + wv[2]*as[2] + wv[3]*as[3];
        pv += wv[0]*ad[0] + wv[1]*ad[1] + wv[2]*ad[2] + wv[3]*ad[3];
    }
    pr[kl][seg] = ps; pd[kl][seg] = pv;
    __syncthreads();
    if (t < 32) {
        float s = 0.f, d = 0.f;
        #pragma unroll
        for (int j = 0; j < 8; ++j) { s += pr[t][j]; d += pd[t][j]; }
        wa[blockIdx.x * 32 + t]       = s;
        wa[256 + blockIdx.x * 32 + t] = d;
    }
    if (blockIdx.x == 0 && t < 8) md_key[t] = 0u;   // key(-inf)
}

// ---------------------------------------------------------------------------
// Kernel 1: Wp = bf16(h@W) in PACKED MFMA-B-fragment layout:
//   elem index ((b*64 + v)*8 + nt)*512 + lane*8 + e, where for feature f and
//   node n: v=n>>5, nt=f>>4, lane=((n>>3)&3)*16 + (f&15), e=n&7.
// s_src/s_dst fp32-exact via wa; per-batch max(s_dst) via uint atomicMax.
// ---------------------------------------------------------------------------
__global__ __launch_bounds__(256) void gat_wh(
        const float* __restrict__ h, const float* __restrict__ W,
        const float* __restrict__ wa, unsigned short* __restrict__ Wp,
        float* __restrict__ s_src, float* __restrict__ s_dst,
        unsigned int* __restrict__ md_key)
{
    __shared__ unsigned short WT[FO][264];  // [f][k] bf16, padded
    __shared__ float wal[512];
    __shared__ float sred[64][4][2];
    __shared__ float red64[64];
    const int t  = threadIdx.x;
    const int b  = blockIdx.x & 7;
    const int n0 = (blockIdx.x >> 3) << 6;

    if (t < 128) *(f32x4*)&wal[t * 4] = *(const f32x4*)&wa[t * 4];
    #pragma unroll
    for (int c = 0; c < 32; ++c) {
        int flat = c * 1024 + t * 4;
        int k = flat >> 7, f = flat & 127;
        f32x4 wv = *(const f32x4*)&W[flat];
        WT[f + 0][k] = f2bf(wv[0]);
        WT[f + 1][k] = f2bf(wv[1]);
        WT[f + 2][k] = f2bf(wv[2]);
        WT[f + 3][k] = f2bf(wv[3]);
    }
    __syncthreads();

    {
        const int row = t >> 2, seg = t & 3;
        const float* hp  = h + ((size_t)(b * Nn + n0 + row)) * FIN + seg * 64;
        const float* was = &wal[seg * 64];
        const float* wad = &wal[256 + seg * 64];
        float ps = 0.f, pv = 0.f;
        #pragma unroll
        for (int j = 0; j < 64; j += 4) {
            f32x4 hv = *(const f32x4*)(hp + j);
            f32x4 sv = *(const f32x4*)(was + j);
            f32x4 dv = *(const f32x4*)(wad + j);
            ps += hv[0]*sv[0] + hv[1]*sv[1] + hv[2]*sv[2] + hv[3]*sv[3];
            pv += hv[0]*dv[0] + hv[1]*dv[1] + hv[2]*dv[2] + hv[3]*dv[3];
        }
        sred[row][seg][0] = ps;
        sred[row][seg][1] = pv;
    }
    __syncthreads();
    if (t < 64) {
        float s = sred[t][0][0] + sred[t][1][0] + sred[t][2][0] + sred[t][3][0];
        float d = sred[t][0][1] + sred[t][1][1] + sred[t][2][1] + sred[t][3][1];
        s_src[b * Nn + n0 + t] = s;
        s_dst[b * Nn + n0 + t] = d;
        red64[t] = d;
    }
    __syncthreads();
    if (t < 16) red64[t] = fmaxf(fmaxf(red64[t], red64[t + 16]),
                                 fmaxf(red64[t + 32], red64[t + 48]));
    __syncthreads();
    if (t == 0) {
        float m = red64[0];
        #pragma unroll
        for (int j = 1; j < 16; ++j) m = fmaxf(m, red64[j]);
        unsigned int bits = __builtin_bit_cast(unsigned int, m);
        unsigned int key  = (bits & 0x80000000u) ? ~bits : (bits | 0x80000000u);
        atomicMax(md_key + b, key);
    }

    const int w = t >> 6, lane = t & 63, n16 = lane & 15, quad = lane >> 4;
    const float* ha = h + ((size_t)(b * Nn + n0 + w * 16 + n16)) * FIN + quad * 8;
    f32x4 acc[8] = {};
    #pragma unroll
    for (int ks = 0; ks < 8; ++ks) {
        f32x4 h0 = *(const f32x4*)(ha + ks * 32);
        f32x4 h1 = *(const f32x4*)(ha + ks * 32 + 4);
        bf16x8 af;
        af[0] = (short)f2bf(h0[0]); af[1] = (short)f2bf(h0[1]);
        af[2] = (short)f2bf(h0[2]); af[3] = (short)f2bf(h0[3]);
        af[4] = (short)f2bf(h1[0]); af[5] = (short)f2bf(h1[1]);
        af[6] = (short)f2bf(h1[2]); af[7] = (short)f2bf(h1[3]);
        #pragma unroll
        for (int nt = 0; nt < 8; ++nt) {
            bf16x8 bfr = *(const bf16x8*)&WT[nt * 16 + n16][ks * 32 + quad * 8];
            acc[nt] = __builtin_amdgcn_mfma_f32_16x16x32_bf16(af, bfr, acc[nt], 0, 0, 0);
        }
    }
    // packed write: element (f = nt*16+n16, n = n0 + w*16 + quad*4 + rr)
    {
        const int v      = (n0 >> 5) + (w >> 1);
        const int quad_p = ((w & 1) << 1) + (quad >> 1);
        const int eoff   = (quad & 1) << 2;
        #pragma unroll
        for (int nt = 0; nt < 8; ++nt) {
            ushort4 pk;
            pk.x = f2bf(acc[nt][0]); pk.y = f2bf(acc[nt][1]);
            pk.z = f2bf(acc[nt][2]); pk.w = f2bf(acc[nt][3]);
            size_t idx = ((((size_t)(b << 6) + v) * 8 + nt) * 64 + quad_p * 16 + n16) * 8 + eoff;
            *(ushort4*)&Wp[idx] = pk;
        }
    }
}

// ---------------------------------------------------------------------------
// Kernel 2 (v12): v10's fused adj-ballot structure + v11's counted-vmcnt
// bare-barrier pipeline, BOTH streams 2 tiles deep.
// Grid 256 = 32 i-tiles(64 rows) x 8 batches (batch==XCD), 512 thr =
// 2 row-groups x 4 j-windows, 16 x 128-j tiles. Per tile s:
//   issue adj loads for s+2 | issue Wp loads for s+2 | compute tile s
//   | ballot s+1 (loads had a FULL tile to cover HBM latency) | ds_write
//   Wp s+1 | lgkmcnt(0) + bare s_barrier.
// vmcnt waits are always counted (>=16 outstanding), never drain to 0;
// loads stay in flight across barriers. Numerics identical to v10.
// ---------------------------------------------------------------------------
__global__ __launch_bounds__(512, 1) void gat_attn(
        const int* __restrict__ adj, const unsigned short* __restrict__ Wp,
        const float* __restrict__ s_src, const float* __restrict__ s_dst,
        const unsigned int* __restrict__ md_key, float* __restrict__ out)
{
    constexpr int AS = 132;                      // accbuf row stride (f32)
    constexpr int MS = 68;                       // mask row stride (words)
    __shared__ __align__(16) float smem_f[2 * 64 * AS];     // 67584 B: stage dbuf / acc slots
    __shared__ __align__(16) unsigned int mlds[64 * MS];    // 17408 B
    __shared__ __align__(16) float dlds[Nn];                // 8192 B
    __shared__ float l_red[64];
    unsigned short* ldsw = (unsigned short*)smem_f;         // 2 x 16384 shorts

    const int t = threadIdx.x, w = t >> 6, lane = t & 63;
    const int n16 = lane & 15, quad = lane >> 4;
    const int rg = w & 1, jwin = w >> 1;         // 2 row-groups x 4 j-windows
    const int b  = blockIdx.x & 7;
    const int i0 = (blockIdx.x >> 3) << 6;

    if (t < 64) l_red[t] = 0.f;

    // per-wave adj base: wave w ballot-packs local rows [w*8, w*8+8)
    const int* abase = adj + ((size_t)(b * Nn + i0 + w * 8)) * Nn + lane;
    const unsigned short* wsrc = Wp + ((size_t)b << 18);

    // ---- prologue ----
    // adj tile-0 loads (balloted below) and tile-1 loads (balloted at s=0)
    int av0[16], avC[16], avN[16];
    #pragma unroll
    for (int k = 0; k < 16; ++k)
        av0[k] = abase[(size_t)(k >> 1) * Nn + ((k & 1) << 6)];
    #pragma unroll
    for (int k = 0; k < 16; ++k)
        avC[k] = abase[(size_t)(k >> 1) * Nn + 128 + ((k & 1) << 6)];
    // Wp tile-0 (staged now) and tile-1 (held in regs, written at s=0)
    f32x4 g0[4], gA[4], gB[4];
    #pragma unroll
    for (int p = 0; p < 4; ++p)
        g0[p] = *(const f32x4*)(wsrc + p * 4096 + t * 8);
    #pragma unroll
    for (int p = 0; p < 4; ++p)
        gA[p] = *(const f32x4*)(wsrc + 16384 + p * 4096 + t * 8);
    // s_dst stage
    *(f32x4*)&dlds[t * 4] = *(const f32x4*)(s_dst + b * Nn + t * 4);

    const unsigned int key = md_key[b];
    const unsigned int mb_ = (key & 0x80000000u) ? (key ^ 0x80000000u) : ~key;
    const float mdb = __builtin_bit_cast(float, mb_);
    const int r0 = i0 + rg * 32 + n16;           // lane's first i-row
    const float ssr0 = s_src[b * Nn + r0];
    const float ssr1 = s_src[b * Nn + r0 + 16];
    const float tm0 = ssr0 + mdb, tm1 = ssr1 + mdb;
    const float mi0 = fmaxf(tm0, GAT_ALPHA * tm0) * LOG2E;
    const float mi1 = fmaxf(tm1, GAT_ALPHA * tm1) * LOG2E;
    const float sL0 = ssr0 * LOG2E, sL1 = ssr1 * LOG2E;
    const int jw = (jwin << 5) + (quad << 3);    // lane's j offset in 128-j tile
    const int mrow0 = (rg * 32 + n16) * MS;
    const int mrow1 = mrow0 + 16 * MS;

    // ballot tile 0 + mask write
    #pragma unroll
    for (int k = 0; k < 16; ++k) {
        unsigned long long m = __ballot(av0[k] > 0);
        const int rr = k >> 1, c = k & 1;
        if (lane == 0) mlds[(w * 8 + rr) * MS + (c << 1)]     = (unsigned int)m;
        if (lane == 1) mlds[(w * 8 + rr) * MS + (c << 1) + 1] = (unsigned int)(m >> 32);
    }
    // Wp tile-0 ds_write (conflict-free linear, 4 passes of 16 B/thread)
    #pragma unroll
    for (int p = 0; p < 4; ++p)
        *(f32x4*)&ldsw[p * 4096 + t * 8] = g0[p];

    f32x4 acc[2][8] = {};
    float ls0 = 0.f, ls1 = 0.f;
    __syncthreads();

    // ---- main loop: 16 x 128-j tiles, 2-deep on both streams ----
#define GAT_TILE(S, CUR, AVC, AVN, GP, GN)                                      \
    {                                                                           \
        const int s_ = (S);                                                     \
        const int j0 = s_ << 7;                                                 \
        /* issue adj loads for tile s+2 (full-tile latency cover) */            \
        if (s_ < 14) {                                                          \
            const int coff = (s_ + 2) << 7;                                     \
            _Pragma("unroll")                                                   \
            for (int k = 0; k < 16; ++k)                                        \
                AVN[k] = abase[(size_t)(k >> 1) * Nn + coff + ((k & 1) << 6)];  \
        }                                                                       \
        /* issue Wp loads for tile s+2 (cross the barrier in flight) */         \
        if (s_ < 14) {                                                          \
            const unsigned short* src = wsrc + (size_t)(s_ + 2) * 16384;        \
            _Pragma("unroll")                                                   \
            for (int p = 0; p < 4; ++p)                                         \
                GN[p] = *(const f32x4*)(src + p * 4096 + t * 8);                \
        }                                                                       \
        /* compute tile s from LDS */                                           \
        const unsigned int mw0 = mlds[mrow0 + (s_ << 2) + jwin];                \
        const unsigned int mw1 = mlds[mrow1 + (s_ << 2) + jwin];                \
        const unsigned int mb0 = (mw0 >> (quad << 3)) & 0xffu;                  \
        const unsigned int mb1 = (mw1 >> (quad << 3)) & 0xffu;                  \
        f32x4 d0 = *(const f32x4*)&dlds[j0 + jw];                               \
        f32x4 d1 = *(const f32x4*)&dlds[j0 + jw + 4];                           \
        bf16x8 af0, af1;                                                        \
        _Pragma("unroll")                                                       \
        for (int j = 0; j < 4; ++j) {                                           \
            {   float u  = __builtin_fmaf(d0[j], LOG2E, sL0);                   \
                float lr = fmaxf(u, GAT_ALPHA * u);                             \
                float e  = __builtin_amdgcn_exp2f(lr - mi0);                    \
                e = ((mb0 >> j) & 1u) ? e : 0.f;                                \
                unsigned short us = f2bf(e);                                    \
                ls0 += bf2f(us); af0[j] = (short)us; }                          \
            {   float u  = __builtin_fmaf(d1[j], LOG2E, sL0);                   \
                float lr = fmaxf(u, GAT_ALPHA * u);                             \
                float e  = __builtin_amdgcn_exp2f(lr - mi0);                    \
                e = ((mb0 >> (4 + j)) & 1u) ? e : 0.f;                          \
                unsigned short us = f2bf(e);                                    \
                ls0 += bf2f(us); af0[4 + j] = (short)us; }                      \
            {   float u  = __builtin_fmaf(d0[j], LOG2E, sL1);                   \
                float lr = fmaxf(u, GAT_ALPHA * u);                             \
                float e  = __builtin_amdgcn_exp2f(lr - mi1);                    \
                e = ((mb1 >> j) & 1u) ? e : 0.f;                                \
                unsigned short us = f2bf(e);                                    \
                ls1 += bf2f(us); af1[j] = (short)us; }                          \
            {   float u  = __builtin_fmaf(d1[j], LOG2E, sL1);                   \
                float lr = fmaxf(u, GAT_ALPHA * u);                             \
                float e  = __builtin_amdgcn_exp2f(lr - mi1);                    \
                e = ((mb1 >> (4 + j)) & 1u) ? e : 0.f;                          \
                unsigned short us = f2bf(e);                                    \
                ls1 += bf2f(us); af1[4 + j] = (short)us; }                      \
        }                                                                       \
        const unsigned short* bbase = &ldsw[(CUR) * 16384 + (jwin << 12) + (lane << 3)]; \
        _Pragma("unroll")                                                       \
        for (int nt = 0; nt < 8; ++nt) {                                        \
            bf16x8 bfr = *(const bf16x8*)(bbase + (nt << 9));                   \
            acc[0][nt] = __builtin_amdgcn_mfma_f32_16x16x32_bf16(af0, bfr, acc[0][nt], 0, 0, 0); \
            acc[1][nt] = __builtin_amdgcn_mfma_f32_16x16x32_bf16(af1, bfr, acc[1][nt], 0, 0, 0); \
        }                                                                       \
        /* ballot tile s+1 (loads issued at tile s-1: full tile of cover) */    \
        if (s_ < 15) {                                                          \
            _Pragma("unroll")                                                   \
            for (int k = 0; k < 16; ++k) {                                      \
                unsigned long long m = __ballot(AVC[k] > 0);                    \
                const int rr = k >> 1, c = k & 1;                               \
                const int wd = ((s_ + 1) << 2) + (c << 1);                      \
                if (lane == 0) mlds[(w * 8 + rr) * MS + wd]     = (unsigned int)m; \
                if (lane == 1) mlds[(w * 8 + rr) * MS + wd + 1] = (unsigned int)(m >> 32); \
            }                                                                   \
        }                                                                       \
        /* ds_write Wp tile s+1 (loaded at tile s-1) into other buffer */       \
        if (s_ < 15) {                                                          \
            _Pragma("unroll")                                                   \
            for (int p = 0; p < 4; ++p)                                         \
                *(f32x4*)&ldsw[((CUR) ^ 1) * 16384 + p * 4096 + t * 8] = GP[p]; \
        }                                                                       \
        asm volatile("s_waitcnt lgkmcnt(0)" ::: "memory");                      \
        __builtin_amdgcn_s_barrier();                                           \
    }

    for (int s = 0; s < 16; s += 2) {
        GAT_TILE(s,     0, avC, avN, gA, gB)
        GAT_TILE(s + 1, 1, avN, avC, gB, gA)
    }
#undef GAT_TILE

    // denominator: reduce per-lane partials across quads, atomics per wave
    ls0 += __shfl_xor(ls0, 16); ls0 += __shfl_xor(ls0, 32);
    ls1 += __shfl_xor(ls1, 16); ls1 += __shfl_xor(ls1, 32);
    if (quad == 0) {
        atomicAdd(&l_red[rg * 32 + n16], ls0);
        atomicAdd(&l_red[rg * 32 + 16 + n16], ls1);
    }

    // cross-wave acc reduction: jwin 0/1 write slots A/B; jwin 2/3 add
    float* slot = smem_f + (size_t)(jwin & 1) * (64 * AS);
    const int rbase = rg * 32;
    if (jwin < 2) {
        #pragma unroll
        for (int ig = 0; ig < 2; ++ig)
            #pragma unroll
            for (int nt = 0; nt < 8; ++nt)
                #pragma unroll
                for (int rr = 0; rr < 4; ++rr)
                    slot[(size_t)(rbase + ig * 16 + quad * 4 + rr) * AS + nt * 16 + n16] = acc[ig][nt][rr];
    }
    __syncthreads();
    if (jwin >= 2) {
        #pragma unroll
        for (int ig = 0; ig < 2; ++ig)
            #pragma unroll
            for (int nt = 0; nt < 8; ++nt)
                #pragma unroll
                for (int rr = 0; rr < 4; ++rr)
                    slot[(size_t)(rbase + ig * 16 + quad * 4 + rr) * AS + nt * 16 + n16] += acc[ig][nt][rr];
    }
    __syncthreads();

    // normalize + ELU + coalesced store (64 rows x 128 f)
    float* ob = out + ((size_t)(b * Nn + i0)) * FO;
    #pragma unroll
    for (int c = 0; c < 4; ++c) {
        int flat = c * 2048 + t * 4;
        int m = flat >> 7, f = flat & 127;
        f32x4 v0 = *(const f32x4*)&smem_f[(size_t)m * AS + f];
        f32x4 v1 = *(const f32x4*)&smem_f[(size_t)(64 + m) * AS + f];
        float l = l_red[m];
        f32x4 o;
        #pragma unroll
        for (int j = 0; j < 4; ++j) {
            float x = (v0[j] + v1[j]) / l;
            o[j] = x > 0.f ? x : expm1f(x);
        }
        *(f32x4*)&ob[(size_t)m * FO + f] = o;
    }
}

extern "C" void kernel_launch(void* const* d_in, const int* in_sizes, int n_in,
                              void* d_out, int out_size, void* d_ws, size_t ws_size,
                              hipStream_t stream)
{
    const float* h   = (const float*)d_in[0];
    const int*   adj = (const int*)d_in[1];
    const float* W   = (const float*)d_in[2];
    const float* a   = (const float*)d_in[3];
    float* out = (float*)d_out;

    char* ws = (char*)d_ws;
    unsigned short* Wp  = (unsigned short*)ws;                    // 4 MiB packed
    float* s_src        = (float*)(ws + 4194304);                 // 8 KiB
    float* s_dst        = (float*)(ws + 4259840);                 // 8 KiB
    float* wa           = (float*)(ws + 4325376);                 // 2 KiB
    unsigned int* md_key= (unsigned int*)(ws + 4327424);          // 32 B

    hipLaunchKernelGGL(gat_prep, dim3(8),   dim3(256), 0, stream, W, a, wa, md_key);
    hipLaunchKernelGGL(gat_wh,   dim3(256), dim3(256), 0, stream, h, W, wa, Wp, s_src, s_dst, md_key);
    hipLaunchKernelGGL(gat_attn, dim3(256), dim3(512), 0, stream, adj, Wp, s_src, s_dst, md_key, out);
}

// Round 10
// 233.972 us; speedup vs baseline: 1.0557x; 1.0098x over previous
//
#include <hip/hip_runtime.h>
#include <hip/hip_bf16.h>

#define GAT_ALPHA 0.2f
#define LOG2E 1.4426950408889634f

typedef float f32x4 __attribute__((ext_vector_type(4)));
typedef int   i32x4 __attribute__((ext_vector_type(4)));
typedef short bf16x8 __attribute__((ext_vector_type(8)));

static constexpr int Nn  = 2048;
static constexpr int FIN = 256;
static constexpr int FO  = 128;

static __device__ __forceinline__ unsigned short f2bf(float x) {
    __hip_bfloat16 h = __float2bfloat16(x);
    return __builtin_bit_cast(unsigned short, h);
}
static __device__ __forceinline__ float bf2f(unsigned short u) {
    unsigned int v = ((unsigned int)u) << 16;
    return __builtin_bit_cast(float, v);
}

// ---------------------------------------------------------------------------
// Kernel 0 (prep): wa = W@a (both halves). Inits md_key[8] = 0 (key of -inf).
// ---------------------------------------------------------------------------
__global__ __launch_bounds__(256) void gat_prep(
        const float* __restrict__ W, const float* __restrict__ a,
        float* __restrict__ wa, unsigned int* __restrict__ md_key)
{
    __shared__ float pr[32][8];
    __shared__ float pd[32][8];
    const int t = threadIdx.x;
    const int kl = t >> 3, seg = t & 7;
    const int k = blockIdx.x * 32 + kl;
    float ps = 0.f, pv = 0.f;
    const float* wr = W + (size_t)k * FO + seg * 16;
    #pragma unroll
    for (int f = 0; f < 16; f += 4) {
        f32x4 wv = *(const f32x4*)(wr + f);
        f32x4 as = *(const f32x4*)(a + seg * 16 + f);
        f32x4 ad = *(const f32x4*)(a + FO + seg * 16 + f);
        ps += wv[0]*as[0] + wv[1]*as[1] + wv[2]*as[2] + wv[3]*as[3];
        pv += wv[0]*ad[0] + wv[1]*ad[1] + wv[2]*ad[2] + wv[3]*ad[3];
    }
    pr[kl][seg] = ps; pd[kl][seg] = pv;
    __syncthreads();
    if (t < 32) {
        float s = 0.f, d = 0.f;
        #pragma unroll
        for (int j = 0; j < 8; ++j) { s += pr[t][j]; d += pd[t][j]; }
        wa[blockIdx.x * 32 + t]       = s;
        wa[256 + blockIdx.x * 32 + t] = d;
    }
    if (blockIdx.x == 0 && t < 8) md_key[t] = 0u;   // key(-inf)
}

// ---------------------------------------------------------------------------
// Kernel 1: Wp = bf16(h@W) in PACKED MFMA-B-fragment layout:
//   elem index ((b*64 + v)*8 + nt)*512 + lane*8 + e, where for feature f and
//   node n: v=n>>5, nt=f>>4, lane=((n>>3)&3)*16 + (f&15), e=n&7.
// s_src/s_dst fp32-exact via wa; per-batch max(s_dst) via uint atomicMax.
// ---------------------------------------------------------------------------
__global__ __launch_bounds__(256) void gat_wh(
        const float* __restrict__ h, const float* __restrict__ W,
        const float* __restrict__ wa, unsigned short* __restrict__ Wp,
        float* __restrict__ s_src, float* __restrict__ s_dst,
        unsigned int* __restrict__ md_key)
{
    __shared__ unsigned short WT[FO][264];  // [f][k] bf16, padded
    __shared__ float wal[512];
    __shared__ float sred[64][4][2];
    __shared__ float red64[64];
    const int t  = threadIdx.x;
    const int b  = blockIdx.x & 7;
    const int n0 = (blockIdx.x >> 3) << 6;

    if (t < 128) *(f32x4*)&wal[t * 4] = *(const f32x4*)&wa[t * 4];
    #pragma unroll
    for (int c = 0; c < 32; ++c) {
        int flat = c * 1024 + t * 4;
        int k = flat >> 7, f = flat & 127;
        f32x4 wv = *(const f32x4*)&W[flat];
        WT[f + 0][k] = f2bf(wv[0]);
        WT[f + 1][k] = f2bf(wv[1]);
        WT[f + 2][k] = f2bf(wv[2]);
        WT[f + 3][k] = f2bf(wv[3]);
    }
    __syncthreads();

    {
        const int row = t >> 2, seg = t & 3;
        const float* hp  = h + ((size_t)(b * Nn + n0 + row)) * FIN + seg * 64;
        const float* was = &wal[seg * 64];
        const float* wad = &wal[256 + seg * 64];
        float ps = 0.f, pv = 0.f;
        #pragma unroll
        for (int j = 0; j < 64; j += 4) {
            f32x4 hv = *(const f32x4*)(hp + j);
            f32x4 sv = *(const f32x4*)(was + j);
            f32x4 dv = *(const f32x4*)(wad + j);
            ps += hv[0]*sv[0] + hv[1]*sv[1] + hv[2]*sv[2] + hv[3]*sv[3];
            pv += hv[0]*dv[0] + hv[1]*dv[1] + hv[2]*dv[2] + hv[3]*dv[3];
        }
        sred[row][seg][0] = ps;
        sred[row][seg][1] = pv;
    }
    __syncthreads();
    if (t < 64) {
        float s = sred[t][0][0] + sred[t][1][0] + sred[t][2][0] + sred[t][3][0];
        float d = sred[t][0][1] + sred[t][1][1] + sred[t][2][1] + sred[t][3][1];
        s_src[b * Nn + n0 + t] = s;
        s_dst[b * Nn + n0 + t] = d;
        red64[t] = d;
    }
    __syncthreads();
    if (t < 16) red64[t] = fmaxf(fmaxf(red64[t], red64[t + 16]),
                                 fmaxf(red64[t + 32], red64[t + 48]));
    __syncthreads();
    if (t == 0) {
        float m = red64[0];
        #pragma unroll
        for (int j = 1; j < 16; ++j) m = fmaxf(m, red64[j]);
        unsigned int bits = __builtin_bit_cast(unsigned int, m);
        unsigned int key  = (bits & 0x80000000u) ? ~bits : (bits | 0x80000000u);
        atomicMax(md_key + b, key);
    }

    const int w = t >> 6, lane = t & 63, n16 = lane & 15, quad = lane >> 4;
    const float* ha = h + ((size_t)(b * Nn + n0 + w * 16 + n16)) * FIN + quad * 8;
    f32x4 acc[8] = {};
    #pragma unroll
    for (int ks = 0; ks < 8; ++ks) {
        f32x4 h0 = *(const f32x4*)(ha + ks * 32);
        f32x4 h1 = *(const f32x4*)(ha + ks * 32 + 4);
        bf16x8 af;
        af[0] = (short)f2bf(h0[0]); af[1] = (short)f2bf(h0[1]);
        af[2] = (short)f2bf(h0[2]); af[3] = (short)f2bf(h0[3]);
        af[4] = (short)f2bf(h1[0]); af[5] = (short)f2bf(h1[1]);
        af[6] = (short)f2bf(h1[2]); af[7] = (short)f2bf(h1[3]);
        #pragma unroll
        for (int nt = 0; nt < 8; ++nt) {
            bf16x8 bfr = *(const bf16x8*)&WT[nt * 16 + n16][ks * 32 + quad * 8];
            acc[nt] = __builtin_amdgcn_mfma_f32_16x16x32_bf16(af, bfr, acc[nt], 0, 0, 0);
        }
    }
    // packed write: element (f = nt*16+n16, n = n0 + w*16 + quad*4 + rr)
    {
        const int v      = (n0 >> 5) + (w >> 1);
        const int quad_p = ((w & 1) << 1) + (quad >> 1);
        const int eoff   = (quad & 1) << 2;
        #pragma unroll
        for (int nt = 0; nt < 8; ++nt) {
            ushort4 pk;
            pk.x = f2bf(acc[nt][0]); pk.y = f2bf(acc[nt][1]);
            pk.z = f2bf(acc[nt][2]); pk.w = f2bf(acc[nt][3]);
            size_t idx = ((((size_t)(b << 6) + v) * 8 + nt) * 64 + quad_p * 16 + n16) * 8 + eoff;
            *(ushort4*)&Wp[idx] = pk;
        }
    }
}

// ---------------------------------------------------------------------------
// Kernel 2 (v13): producer-consumer wave specialization.
// Grid 256 = 32 i-tiles(64 rows) x 8 batches, 1 block/CU, 768 threads:
//   waves 0-7  = CONSUMERS (2 row-groups x 4 j-windows, v10 math): no
//                global loads, no barriers in the loop — spin on ring flag,
//                read mask/d/B-frags from LDS, exp + 16 MFMA per tile.
//   waves 8-11 = PRODUCERS: stream adj (32 loads -> 32 ballots -> mask ring)
//                and Wp (8x16B loads -> LDS ring) continuously, up to 3
//                tiles ahead. Memory never idles behind compute phases.
// 3-slot ring, monotonic LDS counters (bounded-buffer protocol):
//   consumer tile s waits prod_flag[s%3] >= 4*(s/3+1);
//   producer tile s (s>=3) waits cons_flag[s%3] >= 8*(s/3).
// Spin loops carry an iteration guard (no-hang safety). Numerics identical
// to v10 (same ballots, exp path, bf16 rounding, denominator order).
// ---------------------------------------------------------------------------
__global__ __launch_bounds__(768, 1) void gat_attn(
        const int* __restrict__ adj, const unsigned short* __restrict__ Wp,
        const float* __restrict__ s_src, const float* __restrict__ s_dst,
        const unsigned int* __restrict__ md_key, float* __restrict__ out)
{
    constexpr int AS = 132;                      // accbuf row stride (f32)
    constexpr int MR = 320;                      // mask ring slot stride (words)
    __shared__ __align__(16) float smem_f[24576];           // 98304 B: Wp ring (3x32KB) / acc alias
    __shared__ __align__(16) unsigned int mring[3 * MR];    // 3840 B mask ring
    __shared__ __align__(16) float dlds[Nn];                // 8192 B
    __shared__ float l_red[64];
    __shared__ unsigned int prod_flag[3], cons_flag[3];
    unsigned short* ldsw = (unsigned short*)smem_f;         // 3 x 16384 shorts

    const int t = threadIdx.x, w = t >> 6, lane = t & 63;
    const int n16 = lane & 15, quad = lane >> 4;
    const int b  = blockIdx.x & 7;
    const int i0 = (blockIdx.x >> 3) << 6;

    if (t < 3) { prod_flag[t] = 0u; cons_flag[t] = 0u; }
    if (t < 64) l_red[t] = 0.f;
    if (t < 512) *(f32x4*)&dlds[t * 4] = *(const f32x4*)(s_dst + b * Nn + t * 4);

    const unsigned short* wsrc = Wp + ((size_t)b << 18);
    __syncthreads();

    f32x4 acc[2][8] = {};
    float ls0 = 0.f, ls1 = 0.f;
    const int rg = w & 1, jwin = w >> 1;         // consumer roles (w < 8)

    if (w < 8) {
        // ===================== CONSUMERS =====================
        const unsigned int key = md_key[b];
        const unsigned int mb_ = (key & 0x80000000u) ? (key ^ 0x80000000u) : ~key;
        const float mdb = __builtin_bit_cast(float, mb_);
        const int r0 = i0 + rg * 32 + n16;
        const float ssr0 = s_src[b * Nn + r0];
        const float ssr1 = s_src[b * Nn + r0 + 16];
        const float tm0 = ssr0 + mdb, tm1 = ssr1 + mdb;
        const float mi0 = fmaxf(tm0, GAT_ALPHA * tm0) * LOG2E;
        const float mi1 = fmaxf(tm1, GAT_ALPHA * tm1) * LOG2E;
        const float sL0 = ssr0 * LOG2E, sL1 = ssr1 * LOG2E;
        const int jw = (jwin << 5) + (quad << 3);
        const int mr0 = (rg * 32 + n16) * 5 + jwin;
        const int mr1 = mr0 + 16 * 5;

        for (int s = 0; s < 16; ++s) {
            const int slot = s % 3;
            const unsigned int ptarget = 4u * (unsigned int)(s / 3 + 1);
            {
                volatile unsigned int* pf = &prod_flag[slot];
                int guard = 0;
                while (*pf < ptarget && guard < (1 << 26)) {
                    ++guard; __builtin_amdgcn_s_sleep(2);
                }
            }
            const int j0 = s << 7;
            const unsigned int mw0 = mring[slot * MR + mr0];
            const unsigned int mw1 = mring[slot * MR + mr1];
            const unsigned int mb0 = (mw0 >> (quad << 3)) & 0xffu;
            const unsigned int mb1 = (mw1 >> (quad << 3)) & 0xffu;
            f32x4 d0 = *(const f32x4*)&dlds[j0 + jw];
            f32x4 d1 = *(const f32x4*)&dlds[j0 + jw + 4];

            bf16x8 af0, af1;
            #pragma unroll
            for (int j = 0; j < 4; ++j) {
                {   float u  = __builtin_fmaf(d0[j], LOG2E, sL0);
                    float lr = fmaxf(u, GAT_ALPHA * u);
                    float e  = __builtin_amdgcn_exp2f(lr - mi0);
                    e = ((mb0 >> j) & 1u) ? e : 0.f;
                    unsigned short us = f2bf(e);
                    ls0 += bf2f(us); af0[j] = (short)us; }
                {   float u  = __builtin_fmaf(d1[j], LOG2E, sL0);
                    float lr = fmaxf(u, GAT_ALPHA * u);
                    float e  = __builtin_amdgcn_exp2f(lr - mi0);
                    e = ((mb0 >> (4 + j)) & 1u) ? e : 0.f;
                    unsigned short us = f2bf(e);
                    ls0 += bf2f(us); af0[4 + j] = (short)us; }
                {   float u  = __builtin_fmaf(d0[j], LOG2E, sL1);
                    float lr = fmaxf(u, GAT_ALPHA * u);
                    float e  = __builtin_amdgcn_exp2f(lr - mi1);
                    e = ((mb1 >> j) & 1u) ? e : 0.f;
                    unsigned short us = f2bf(e);
                    ls1 += bf2f(us); af1[j] = (short)us; }
                {   float u  = __builtin_fmaf(d1[j], LOG2E, sL1);
                    float lr = fmaxf(u, GAT_ALPHA * u);
                    float e  = __builtin_amdgcn_exp2f(lr - mi1);
                    e = ((mb1 >> (4 + j)) & 1u) ? e : 0.f;
                    unsigned short us = f2bf(e);
                    ls1 += bf2f(us); af1[4 + j] = (short)us; }
            }

            const unsigned short* bbase = &ldsw[slot * 16384 + (jwin << 12) + (lane << 3)];
            #pragma unroll
            for (int nt = 0; nt < 8; ++nt) {
                bf16x8 bfr = *(const bf16x8*)(bbase + (nt << 9));
                acc[0][nt] = __builtin_amdgcn_mfma_f32_16x16x32_bf16(af0, bfr, acc[0][nt], 0, 0, 0);
                acc[1][nt] = __builtin_amdgcn_mfma_f32_16x16x32_bf16(af1, bfr, acc[1][nt], 0, 0, 0);
            }
            if (lane == 0) atomicAdd(&cons_flag[slot], 1u);
        }
    } else {
        // ===================== PRODUCERS =====================
        const int p = w - 8;                     // 0..3: rows [p*16, p*16+16)
        const int pl = (p << 6) + lane;          // 0..255
        const int* arow0 = adj + ((size_t)(b * Nn + i0 + (p << 4))) * Nn + lane;

        for (int s = 0; s < 16; ++s) {
            const int slot = s % 3;
            const int r = s / 3;
            if (r > 0) {
                const unsigned int ctarget = 8u * (unsigned int)r;
                volatile unsigned int* cf = &cons_flag[slot];
                int guard = 0;
                while (*cf < ctarget && guard < (1 << 26)) {
                    ++guard; __builtin_amdgcn_s_sleep(2);
                }
            }
            const int j0 = s << 7;
            // Wp loads: 8 x 16 B per lane (128 B/lane, 32 KB across 4 waves)
            const unsigned short* src = wsrc + (size_t)s * 16384;
            f32x4 g[8];
            #pragma unroll
            for (int q = 0; q < 8; ++q)
                g[q] = *(const f32x4*)(src + q * 2048 + pl * 8);
            // adj loads: 16 rows x 2 chunks of 64 ints
            int av[32];
            #pragma unroll
            for (int rr = 0; rr < 16; ++rr) {
                av[2 * rr]     = arow0[(size_t)rr * Nn + j0];
                av[2 * rr + 1] = arow0[(size_t)rr * Nn + j0 + 64];
            }
            // ballots -> mask ring
            #pragma unroll
            for (int rr = 0; rr < 16; ++rr) {
                unsigned long long m0 = __ballot(av[2 * rr]     > 0);
                unsigned long long m1 = __ballot(av[2 * rr + 1] > 0);
                const int mbx = slot * MR + ((p << 4) + rr) * 5;
                if (lane == 0) {
                    mring[mbx + 0] = (unsigned int)m0;
                    mring[mbx + 2] = (unsigned int)m1;
                }
                if (lane == 1) {
                    mring[mbx + 1] = (unsigned int)(m0 >> 32);
                    mring[mbx + 3] = (unsigned int)(m1 >> 32);
                }
            }
            // Wp -> ring (conflict-free linear 16 B strides)
            #pragma unroll
            for (int q = 0; q < 8; ++q)
                *(f32x4*)&ldsw[slot * 16384 + q * 2048 + pl * 8] = g[q];
            asm volatile("s_waitcnt lgkmcnt(0)" ::: "memory");
            if (lane == 0) atomicAdd(&prod_flag[slot], 1u);
        }
    }

    // ring retired; realign all 12 waves before aliasing smem_f with accbuf
    __syncthreads();

    if (w < 8) {
        ls0 += __shfl_xor(ls0, 16); ls0 += __shfl_xor(ls0, 32);
        ls1 += __shfl_xor(ls1, 16); ls1 += __shfl_xor(ls1, 32);
        if (quad == 0) {
            atomicAdd(&l_red[rg * 32 + n16], ls0);
            atomicAdd(&l_red[rg * 32 + 16 + n16], ls1);
        }
        // jwin 0/1 write slots A/B
        if (jwin < 2) {
            float* slotp = smem_f + (size_t)(jwin & 1) * (64 * AS);
            const int rbase = rg * 32;
            #pragma unroll
            for (int ig = 0; ig < 2; ++ig)
                #pragma unroll
                for (int nt = 0; nt < 8; ++nt)
                    #pragma unroll
                    for (int rr = 0; rr < 4; ++rr)
                        slotp[(size_t)(rbase + ig * 16 + quad * 4 + rr) * AS + nt * 16 + n16] = acc[ig][nt][rr];
        }
    }
    __syncthreads();
    if (w < 8 && jwin >= 2) {
        float* slotp = smem_f + (size_t)(jwin & 1) * (64 * AS);
        const int rbase = rg * 32;
        #pragma unroll
        for (int ig = 0; ig < 2; ++ig)
            #pragma unroll
            for (int nt = 0; nt < 8; ++nt)
                #pragma unroll
                for (int rr = 0; rr < 4; ++rr)
                    slotp[(size_t)(rbase + ig * 16 + quad * 4 + rr) * AS + nt * 16 + n16] += acc[ig][nt][rr];
    }
    __syncthreads();

    // normalize + ELU + coalesced store (64 rows x 128 f)
    if (t < 512) {
        float* ob = out + ((size_t)(b * Nn + i0)) * FO;
        #pragma unroll
        for (int c = 0; c < 4; ++c) {
            int flat = c * 2048 + t * 4;
            int m = flat >> 7, f = flat & 127;
            f32x4 v0 = *(const f32x4*)&smem_f[(size_t)m * AS + f];
            f32x4 v1 = *(const f32x4*)&smem_f[(size_t)(64 + m) * AS + f];
            float l = l_red[m];
            f32x4 o;
            #pragma unroll
            for (int j = 0; j < 4; ++j) {
                float x = (v0[j] + v1[j]) / l;
                o[j] = x > 0.f ? x : expm1f(x);
            }
            *(f32x4*)&ob[(size_t)m * FO + f] = o;
        }
    }
}

extern "C" void kernel_launch(void* const* d_in, const int* in_sizes, int n_in,
                              void* d_out, int out_size, void* d_ws, size_t ws_size,
                              hipStream_t stream)
{
    const float* h   = (const float*)d_in[0];
    const int*   adj = (const int*)d_in[1];
    const float* W   = (const float*)d_in[2];
    const float* a   = (const float*)d_in[3];
    float* out = (float*)d_out;

    char* ws = (char*)d_ws;
    unsigned short* Wp  = (unsigned short*)ws;                    // 4 MiB packed
    float* s_src        = (float*)(ws + 4194304);                 // 8 KiB
    float* s_dst        = (float*)(ws + 4259840);                 // 8 KiB
    float* wa           = (float*)(ws + 4325376);                 // 2 KiB
    unsigned int* md_key= (unsigned int*)(ws + 4327424);          // 32 B

    hipLaunchKernelGGL(gat_prep, dim3(8),   dim3(256), 0, stream, W, a, wa, md_key);
    hipLaunchKernelGGL(gat_wh,   dim3(256), dim3(256), 0, stream, h, W, wa, Wp, s_src, s_dst, md_key);
    hipLaunchKernelGGL(gat_attn, dim3(256), dim3(768), 0, stream, adj, Wp, s_src, s_dst, md_key, out);
}